// Round 1
// 608.896 us; speedup vs baseline: 1.0767x; 1.0767x over previous
//
#include <hip/hip_runtime.h>
#include <hip/hip_bf16.h>
#include <math.h>

typedef __bf16 bf16x8 __attribute__((ext_vector_type(8)));
typedef float  f32x4  __attribute__((ext_vector_type(4)));
typedef float  f32x16 __attribute__((ext_vector_type(16)));
typedef unsigned short ushort_t;
typedef ushort_t us4 __attribute__((ext_vector_type(4)));

#define MFMA16(a, b, c) __builtin_amdgcn_mfma_f32_16x16x32_bf16((a), (b), (c), 0, 0, 0)
#define MFMA32(a, b, c) __builtin_amdgcn_mfma_f32_32x32x16_bf16((a), (b), (c), 0, 0, 0)

__device__ __forceinline__ float bf2f(ushort_t h) {
    union { unsigned u; float f; } v; v.u = ((unsigned)h) << 16; return v.f;
}
__device__ __forceinline__ ushort_t f2bf(float x) {
    union { float f; unsigned u; } v; v.f = x;
    unsigned r = v.u + 0x7FFFu + ((v.u >> 16) & 1u);
    return (ushort_t)(r >> 16);
}
// async global->LDS, 16B per lane. LDS dest must be wave-uniform base + lane*16.
__device__ __forceinline__ void gl2lds16(const void* g, void* l) {
    __builtin_amdgcn_global_load_lds((__attribute__((address_space(1))) void*)(g),
                                     (__attribute__((address_space(3))) void*)(l),
                                     16, 0, 0);
}

// ---------------------------------------------------------------------------
// Dtype detector (round-3 verified: flag=1 fires, inputs are fp32).
// ---------------------------------------------------------------------------
__global__ __launch_bounds__(256) void detect_kernel(const ushort_t* __restrict__ w, int* flag)
{
    __shared__ int cnt[256];
    const int t = threadIdx.x;
    int c = 0;
    for (int i = t; i < 65536; i += 256) {
        const unsigned hw = w[i];
        const unsigned e = (hw >> 7) & 0xFFu;
        if (e == 0xFFu || (e == 0u && (hw & 0x7Fu) != 0u)) c++;
    }
    cnt[t] = c;
    __syncthreads();
    for (int s = 128; s > 0; s >>= 1) {
        if (t < s) cnt[t] += cnt[t + s];
        __syncthreads();
    }
    if (t == 0) flag[0] = (cnt[0] >= 8) ? 1 : 0;
}

__global__ __launch_bounds__(256) void convert_kernel(const void* __restrict__ src,
                                                      ushort_t* __restrict__ dst,
                                                      int n, const int* __restrict__ flag)
{
    const int i0 = (blockIdx.x * 256 + threadIdx.x) * 8;
    if (i0 + 8 > n) return;
    if (flag[0]) {
        const f32x4 a = *(const f32x4*)((const float*)src + i0);
        const f32x4 b = *(const f32x4*)((const float*)src + i0 + 4);
        ushort_t o[8];
        o[0]=f2bf(a[0]); o[1]=f2bf(a[1]); o[2]=f2bf(a[2]); o[3]=f2bf(a[3]);
        o[4]=f2bf(b[0]); o[5]=f2bf(b[1]); o[6]=f2bf(b[2]); o[7]=f2bf(b[3]);
        *(bf16x8*)(dst + i0) = *(const bf16x8*)o;
    } else {
        *(bf16x8*)(dst + i0) = *(const bf16x8*)((const ushort_t*)src + i0);
    }
}

// ---------------------------------------------------------------------------
// 256x256-tile 8-phase GEMM, C = A * B^T + bias (bf16 in/out).
// 512 thr = 8 waves (2M x 4N); per-wave output 128x64; BK=64 as 2x 32-k chunks.
// LDS = 4-slot ring of chunks, each slot = A 16KB + B 16KB (128 KiB total).
// Schedule ledger (chunk g = 2t+c, slot g&3; 1 stage op = 8KB block-wide/phase):
//   ops of chunk g issued at global phases 4g-9..4g-6 (j0=A0,j1=A1,j2=B0,j3=B1)
//   first ds_read of chunk g at phase 4g (even g) / 4g-3 (odd g)
//   guards: end-p0 vmcnt(2) [odd chunk: 2 younger ops in flight]
//           end-p7 vmcnt(5) [next even chunk: 5 younger ops]  -- never 0 steady
//   tails:  t==NT-2 end-p7 -> vmcnt(4); t==NT-1 end-p0 -> vmcnt(0); no stages.
//   WAR: slot's last ds_read drains before its phase's closing barrier (reads
//   feed same-phase MFMAs -> compiler lgkmcnt), overwriting stage issued >=1
//   barrier later (s0 last read p4, restaged p7; s1 last read p5, restaged
//   next-tile p3; sA prev occupant last read p6 of t-1, restaged p7 of t-1).
// LDS swizzle: 16B unit (row, qs) holds k-octet q = qs ^ ((row>>1)&3); the 16
//   lanes of a frag then cover all 8 bank-groups (~2 lanes/bank = free).
//   Staging realizes it by inverse-swizzling the GLOBAL source (LDS linear).
// ---------------------------------------------------------------------------
__global__ __launch_bounds__(512, 2) void gemm256_bt_bias(
    const ushort_t* __restrict__ A, const ushort_t* __restrict__ B,
    const ushort_t* __restrict__ bias, ushort_t* __restrict__ C,
    int M, int N, int K)
{
    __shared__ __align__(16) ushort_t SM[65536];   // 4 slots x (8192 A + 8192 B) ushorts
    const int tid = threadIdx.x;
    const int l = tid & 63, ln = l & 15, q2 = l >> 4;
    const int w = tid >> 6, wm = w >> 2, wn = w & 3;
    const int m0 = blockIdx.y * 256, n0 = blockIdx.x * 256;
    const int NT = K >> 6;

#define STG_A256(slot, kbase, o) do { \
    const int s_ = (o) * 512 + tid; const int r_ = s_ >> 2; \
    const int q_ = (s_ & 3) ^ ((r_ >> 1) & 3); \
    gl2lds16(A + (size_t)(m0 + r_) * K + (kbase) + q_ * 8, \
             SM + (slot) * 16384 + s_ * 8); } while (0)
#define STG_B256(slot, kbase, o) do { \
    const int s_ = (o) * 512 + tid; const int r_ = s_ >> 2; \
    const int q_ = (s_ & 3) ^ ((r_ >> 1) & 3); \
    gl2lds16(B + (size_t)(n0 + r_) * K + (kbase) + q_ * 8, \
             SM + (slot) * 16384 + 8192 + s_ * 8); } while (0)
#define DSA256(slot, row) (*(const bf16x8*)(SM + (slot) * 16384 + (row) * 32 + ((q2 ^ (((row) >> 1) & 3)) << 3)))
#define DSB256(slot, row) (*(const bf16x8*)(SM + (slot) * 16384 + 8192 + (row) * 32 + ((q2 ^ (((row) >> 1) & 3)) << 3)))
#define BAR256() asm volatile("s_barrier" ::: "memory")

    f32x4 acc[8][4];
    const f32x4 z4 = {0.f, 0.f, 0.f, 0.f};
#pragma unroll
    for (int i = 0; i < 8; i++)
#pragma unroll
        for (int j = 0; j < 4; j++) acc[i][j] = z4;

    // prologue: chunk0 (j0..j3), chunk1 (j0..j3), chunk2 (j0) = 9 stage ops
    STG_A256(0, 0, 0);  STG_A256(0, 0, 1);  STG_B256(0, 0, 0);  STG_B256(0, 0, 1);
    STG_A256(1, 32, 0); STG_A256(1, 32, 1); STG_B256(1, 32, 0); STG_B256(1, 32, 1);
    if (NT > 1) STG_A256(2, 64, 0);
    asm volatile("s_waitcnt vmcnt(5)" ::: "memory");   // chunk0 drained
    BAR256();

    for (int t = 0; t < NT; ++t) {
        const int s0 = (2 * t) & 3, s1 = (2 * t + 1) & 3;
        const int sA = (2 * t + 2) & 3, sB = (2 * t + 3) & 3;   // chunk 2t+4 reuses s0
        const int kA = (t + 1) << 6, kB = kA + 32, kC = (t + 2) << 6;
        const bool stAB = (t < NT - 1), stC = (t < NT - 2);
        const int rA0 = wm * 128, rA1 = wm * 128 + 64, rB = wn * 64;
        bf16x8 a0[4], a1[4], b00[2], b01[2], b10[2], b11[2];

        // ---- p0: (mh0, nh0, k0) -- reads chunk s0
#pragma unroll
        for (int ii = 0; ii < 4; ii++) a0[ii] = DSA256(s0, rA0 + ii * 16 + ln);
        b00[0] = DSB256(s0, rB + ln);
        b00[1] = DSB256(s0, rB + 16 + ln);
        if (stAB) STG_A256(sA, kA, 1);
        __builtin_amdgcn_s_setprio(1);
#pragma unroll
        for (int ii = 0; ii < 4; ii++) {
            acc[ii][0] = MFMA16(a0[ii], b00[0], acc[ii][0]);
            acc[ii][1] = MFMA16(a0[ii], b00[1], acc[ii][1]);
        }
        __builtin_amdgcn_s_setprio(0);
        if (stAB) { asm volatile("s_waitcnt vmcnt(2)" ::: "memory"); }
        else      { asm volatile("s_waitcnt vmcnt(0)" ::: "memory"); }
        BAR256();

        // ---- p1: (mh0, nh0, k1) -- reads chunk s1
#pragma unroll
        for (int ii = 0; ii < 4; ii++) a1[ii] = DSA256(s1, rA0 + ii * 16 + ln);
        b01[0] = DSB256(s1, rB + ln);
        b01[1] = DSB256(s1, rB + 16 + ln);
        if (stAB) STG_B256(sA, kA, 0);
        __builtin_amdgcn_s_setprio(1);
#pragma unroll
        for (int ii = 0; ii < 4; ii++) {
            acc[ii][0] = MFMA16(a1[ii], b01[0], acc[ii][0]);
            acc[ii][1] = MFMA16(a1[ii], b01[1], acc[ii][1]);
        }
        __builtin_amdgcn_s_setprio(0);
        BAR256();

        // ---- p2: (mh0, nh1, k0)
        b10[0] = DSB256(s0, rB + 32 + ln);
        b10[1] = DSB256(s0, rB + 48 + ln);
        if (stAB) STG_B256(sA, kA, 1);
        __builtin_amdgcn_s_setprio(1);
#pragma unroll
        for (int ii = 0; ii < 4; ii++) {
            acc[ii][2] = MFMA16(a0[ii], b10[0], acc[ii][2]);
            acc[ii][3] = MFMA16(a0[ii], b10[1], acc[ii][3]);
        }
        __builtin_amdgcn_s_setprio(0);
        BAR256();

        // ---- p3: (mh0, nh1, k1)
        b11[0] = DSB256(s1, rB + 32 + ln);
        b11[1] = DSB256(s1, rB + 48 + ln);
        if (stAB) STG_A256(sB, kB, 0);
        __builtin_amdgcn_s_setprio(1);
#pragma unroll
        for (int ii = 0; ii < 4; ii++) {
            acc[ii][2] = MFMA16(a1[ii], b11[0], acc[ii][2]);
            acc[ii][3] = MFMA16(a1[ii], b11[1], acc[ii][3]);
        }
        __builtin_amdgcn_s_setprio(0);
        BAR256();

        // ---- p4: (mh1, nh1, k0) -- a0 regs rotate to mh1
#pragma unroll
        for (int ii = 0; ii < 4; ii++) a0[ii] = DSA256(s0, rA1 + ii * 16 + ln);
        if (stAB) STG_A256(sB, kB, 1);
        __builtin_amdgcn_s_setprio(1);
#pragma unroll
        for (int ii = 0; ii < 4; ii++) {
            acc[4 + ii][2] = MFMA16(a0[ii], b10[0], acc[4 + ii][2]);
            acc[4 + ii][3] = MFMA16(a0[ii], b10[1], acc[4 + ii][3]);
        }
        __builtin_amdgcn_s_setprio(0);
        BAR256();

        // ---- p5: (mh1, nh1, k1)
#pragma unroll
        for (int ii = 0; ii < 4; ii++) a1[ii] = DSA256(s1, rA1 + ii * 16 + ln);
        if (stAB) STG_B256(sB, kB, 0);
        __builtin_amdgcn_s_setprio(1);
#pragma unroll
        for (int ii = 0; ii < 4; ii++) {
            acc[4 + ii][2] = MFMA16(a1[ii], b11[0], acc[4 + ii][2]);
            acc[4 + ii][3] = MFMA16(a1[ii], b11[1], acc[4 + ii][3]);
        }
        __builtin_amdgcn_s_setprio(0);
        BAR256();

        // ---- p6: (mh1, nh0, k0) -- all operands in regs
        if (stAB) STG_B256(sB, kB, 1);
        __builtin_amdgcn_s_setprio(1);
#pragma unroll
        for (int ii = 0; ii < 4; ii++) {
            acc[4 + ii][0] = MFMA16(a0[ii], b00[0], acc[4 + ii][0]);
            acc[4 + ii][1] = MFMA16(a0[ii], b00[1], acc[4 + ii][1]);
        }
        __builtin_amdgcn_s_setprio(0);
        BAR256();

        // ---- p7: (mh1, nh0, k1)
        if (stC) STG_A256(s0, kC, 0);   // chunk 2t+4 -> slot s0 (last read was p4)
        __builtin_amdgcn_s_setprio(1);
#pragma unroll
        for (int ii = 0; ii < 4; ii++) {
            acc[4 + ii][0] = MFMA16(a1[ii], b01[0], acc[4 + ii][0]);
            acc[4 + ii][1] = MFMA16(a1[ii], b01[1], acc[4 + ii][1]);
        }
        __builtin_amdgcn_s_setprio(0);
        if (t < NT - 2)       { asm volatile("s_waitcnt vmcnt(5)" ::: "memory"); }
        else if (t == NT - 2) { asm volatile("s_waitcnt vmcnt(4)" ::: "memory"); }
        BAR256();
    }

    // epilogue: bias add, bf16 store (C layout: col = ln, row = q2*4 + r)
#pragma unroll
    for (int j = 0; j < 4; j++) {
        const int n = n0 + wn * 64 + j * 16 + ln;
        const float bv = bf2f(bias[n]);
#pragma unroll
        for (int i = 0; i < 8; i++) {
            const int mrow = m0 + wm * 128 + i * 16 + q2 * 4;
#pragma unroll
            for (int r = 0; r < 4; r++)
                C[(size_t)(mrow + r) * N + n] = f2bf(acc[i][j][r] + bv);
        }
    }
#undef STG_A256
#undef STG_B256
#undef DSA256
#undef DSB256
#undef BAR256
}

// ---------------------------------------------------------------------------
// Final GEMM: fp32 output when flag=1 (verified), bf16 otherwise. (m97-style)
// ---------------------------------------------------------------------------
__global__ __launch_bounds__(256) void gemm_bt_bias_out(
    const ushort_t* __restrict__ A, const ushort_t* __restrict__ B,
    const ushort_t* __restrict__ bias, void* __restrict__ C,
    int M, int N, int K, const int* __restrict__ flag)
{
    __shared__ __align__(16) ushort_t As[128 * 32];
    __shared__ __align__(16) ushort_t Bs[128 * 32];
    const int tid = threadIdx.x;
    const int w = tid >> 6, l = tid & 63, q = l >> 4, ln = l & 15;
    const int wm = w >> 1, wn = w & 1;
    const int m0 = blockIdx.y * 128, n0 = blockIdx.x * 128;
    const int sr = tid >> 2;
    const int sc = (tid & 3) * 8;

    f32x4 acc[4][4];
    const f32x4 z4 = {0.f, 0.f, 0.f, 0.f};
    for (int i = 0; i < 4; i++) for (int j = 0; j < 4; j++) acc[i][j] = z4;

    for (int k0 = 0; k0 < K; k0 += 32) {
        __syncthreads();
        gl2lds16(A + (size_t)(m0 + sr) * K + k0 + sc,       As + sr * 32 + sc);
        gl2lds16(A + (size_t)(m0 + 64 + sr) * K + k0 + sc,  As + (64 + sr) * 32 + sc);
        gl2lds16(B + (size_t)(n0 + sr) * K + k0 + sc,       Bs + sr * 32 + sc);
        gl2lds16(B + (size_t)(n0 + 64 + sr) * K + k0 + sc,  Bs + (64 + sr) * 32 + sc);
        __syncthreads();
        bf16x8 a[4], bb[4];
        for (int i = 0; i < 4; i++)
            a[i]  = *(const bf16x8*)(As + (wm * 64 + i * 16 + ln) * 32 + q * 8);
        for (int j = 0; j < 4; j++)
            bb[j] = *(const bf16x8*)(Bs + (wn * 64 + j * 16 + ln) * 32 + q * 8);
        for (int i = 0; i < 4; i++)
            for (int j = 0; j < 4; j++)
                acc[i][j] = MFMA16(a[i], bb[j], acc[i][j]);
    }
    const int f = flag[0];
    for (int j = 0; j < 4; j++) {
        const int n = n0 + wn * 64 + j * 16 + ln;
        const float bv = bf2f(bias[n]);
        for (int i = 0; i < 4; i++) {
            const int mrow = m0 + wm * 64 + i * 16 + q * 4;
            for (int r = 0; r < 4; r++) {
                const float val = acc[i][j][r] + bv;
                const size_t idx = (size_t)(mrow + r) * N + n;
                if (f) ((float*)C)[idx] = val;
                else   ((ushort_t*)C)[idx] = f2bf(val);
            }
        }
    }
}

// ---------------------------------------------------------------------------
// RoPE (unchanged, verified).
// ---------------------------------------------------------------------------
__global__ __launch_bounds__(256) void rope_kernel(ushort_t* qkv)
{
    const int bs = blockIdx.x;
    const int s = bs & 2047;
    const int t = threadIdx.x;
    const size_t base = (size_t)bs * 6144;
    float cv[8], sv[8], qa[8], qp[8], ka[8], kp[8];
    for (int u = 0; u < 8; u++) {
        const int e = u * 256 + t;
        const int j = e & 127;
        const int p = (j < 64) ? (2 * j + 1) : (2 * (j - 64));
        const int hb = e - j;
        const float ang = powf(10000.0f, -(float)(2 * (j >> 1)) / 2048.0f);
        sincosf((float)s * ang, &sv[u], &cv[u]);
        qa[u] = bf2f(qkv[base + hb + j]);
        qp[u] = bf2f(qkv[base + hb + p]);
        ka[u] = bf2f(qkv[base + 2048 + hb + j]);
        kp[u] = bf2f(qkv[base + 2048 + hb + p]);
    }
    __syncthreads();
    for (int u = 0; u < 8; u++) {
        const int e = u * 256 + t;
        const int j = e & 127;
        const int hb = e - j;
        const float sg = (j < 64) ? -1.0f : 1.0f;
        qkv[base + hb + j]        = f2bf(cv[u] * qa[u] + sv[u] * sg * qp[u]);
        qkv[base + 2048 + hb + j] = f2bf(cv[u] * ka[u] + sv[u] * sg * kp[u]);
    }
}

// ---------------------------------------------------------------------------
// Vt[b,h,d,s] = qkv[b,s,2,h,d] (unchanged, verified).
// ---------------------------------------------------------------------------
__global__ __launch_bounds__(256) void vtrans_kernel(const ushort_t* __restrict__ qkv,
                                                     ushort_t* __restrict__ Vt)
{
    __shared__ ushort_t tile[64][130];
    const int blk = blockIdx.x;
    const int st = blk & 31, h = (blk >> 5) & 15, b = blk >> 9;
    const int t = threadIdx.x;
    for (int i = 0; i < 32; i++) {
        const int e = i * 256 + t;
        const int r = e >> 7, c = e & 127;
        tile[r][c] = qkv[(size_t)(b * 2048 + st * 64 + r) * 6144 + 4096 + h * 128 + c];
    }
    __syncthreads();
    const int d = t >> 1, s0 = (t & 1) * 32;
    const size_t obase = ((size_t)(b * 16 + h) * 128 + d) * 2048 + st * 64 + s0;
    for (int k = 0; k < 32; k++)
        Vt[obase + k] = tile[s0 + k][d];
}

// ---------------------------------------------------------------------------
// Flash attention v2 (unchanged, verified).
// ---------------------------------------------------------------------------
__global__ __launch_bounds__(256) void flash_kernel(
    const ushort_t* __restrict__ qkv, const ushort_t* __restrict__ Vt,
    const int* __restrict__ mask, ushort_t* __restrict__ AO)
{
    __shared__ __align__(16) ushort_t Ks[64 * 136];
    __shared__ __align__(16) ushort_t Vs[128 * 136];
    __shared__ __align__(16) ushort_t Ps[4 * 32 * 72];
    const int t = threadIdx.x;
    const int w = t >> 6, l = t & 63, lq = l & 31, q2 = l >> 5;
    const int qb = blockIdx.x * 128, h = blockIdx.y, b = blockIdx.z;
    const size_t brow = (size_t)b * 2048;
    const float scale = 0.08838834764831845f;   // 1/sqrt(128)
    const int qrow = qb + w * 32 + lq;

    bf16x8 qf[8];
#pragma unroll
    for (int kb = 0; kb < 8; kb++)
        qf[kb] = *(const bf16x8*)(qkv + (brow + qrow) * 6144 + h * 128 + kb * 16 + q2 * 8);

    float m_old = -1e30f, lsum = 0.f;
    f32x16 acc_o[4];
#pragma unroll
    for (int dt = 0; dt < 4; dt++)
#pragma unroll
        for (int r = 0; r < 16; r++) acc_o[dt][r] = 0.f;

    for (int s0 = 0; s0 < 2048; s0 += 64) {
        const int mk = mask[brow + s0 + l];
        const unsigned long long bm = __ballot(mk != 0);
        __syncthreads();
#pragma unroll
        for (int i = 0; i < 4; i++) {
            const int c = i * 256 + t;
            const int row = c >> 4, cb = c & 15;
            *(bf16x8*)(Ks + row * 136 + cb * 8) =
                *(const bf16x8*)(qkv + (brow + s0 + row) * 6144 + 2048 + h * 128 + cb * 8);
        }
#pragma unroll
        for (int i = 0; i < 4; i++) {
            const int c = i * 256 + t;
            const int row = c >> 3, cb = c & 7;
            *(bf16x8*)(Vs + row * 136 + cb * 8) =
                *(const bf16x8*)(Vt + ((size_t)(b * 16 + h) * 128 + row) * 2048 + s0 + cb * 8);
        }
        __syncthreads();
        f32x16 sa[2];
#pragma unroll
        for (int mt = 0; mt < 2; mt++) {
#pragma unroll
            for (int r = 0; r < 16; r++) sa[mt][r] = 0.f;
#pragma unroll
            for (int kb = 0; kb < 8; kb++) {
                bf16x8 a = *(const bf16x8*)(Ks + (mt * 32 + lq) * 136 + kb * 16 + q2 * 8);
                sa[mt] = MFMA32(a, qf[kb], sa[mt]);
            }
        }
        float p[32];
        float mr = -1e30f;
#pragma unroll
        for (int mt = 0; mt < 2; mt++)
#pragma unroll
            for (int r = 0; r < 16; r++) {
                const int srow = mt * 32 + (r & 3) + 8 * (r >> 2) + 4 * q2;
                const float bias = ((bm >> srow) & 1ull) ? 0.f : -1e9f;
                const float v = sa[mt][r] * scale + bias;
                p[mt * 16 + r] = v;
                mr = fmaxf(mr, v);
            }
        mr = fmaxf(mr, __shfl_xor(mr, 32, 64));
        const float mnew = fmaxf(m_old, mr);
        const float alpha = __expf(m_old - mnew);
        float rs = 0.f;
#pragma unroll
        for (int i = 0; i < 32; i++) { p[i] = __expf(p[i] - mnew); rs += p[i]; }
        rs += __shfl_xor(rs, 32, 64);
        lsum = alpha * lsum + rs;
        m_old = mnew;
#pragma unroll
        for (int dt = 0; dt < 4; dt++)
#pragma unroll
            for (int r = 0; r < 16; r++) acc_o[dt][r] *= alpha;
#pragma unroll
        for (int mt = 0; mt < 2; mt++)
#pragma unroll
            for (int r2 = 0; r2 < 4; r2++) {
                us4 pk;
#pragma unroll
                for (int j = 0; j < 4; j++) pk[j] = f2bf(p[mt * 16 + r2 * 4 + j]);
                *(us4*)(Ps + (w * 32 + lq) * 72 + mt * 32 + r2 * 8 + q2 * 4) = pk;
            }
        bf16x8 pf[4];
#pragma unroll
        for (int kb = 0; kb < 4; kb++)
            pf[kb] = *(const bf16x8*)(Ps + (w * 32 + lq) * 72 + kb * 16 + q2 * 8);
#pragma unroll
        for (int dt = 0; dt < 4; dt++)
#pragma unroll
            for (int kb = 0; kb < 4; kb++) {
                bf16x8 va = *(const bf16x8*)(Vs + (dt * 32 + lq) * 136 + kb * 16 + q2 * 8);
                acc_o[dt] = MFMA32(va, pf[kb], acc_o[dt]);
            }
    }
    __syncthreads();
    const float inv = (lsum > 0.f) ? 1.0f / lsum : 0.f;
#pragma unroll
    for (int dt = 0; dt < 4; dt++)
#pragma unroll
        for (int r2 = 0; r2 < 4; r2++) {
            us4 ov;
#pragma unroll
            for (int j = 0; j < 4; j++) ov[j] = f2bf(acc_o[dt][r2 * 4 + j] * inv);
            *(us4*)(Vs + (w * 32 + lq) * 136 + dt * 32 + r2 * 8 + q2 * 4) = ov;
        }
#pragma unroll
    for (int i = 0; i < 8; i++) {
        const int row = i * 4 + (l >> 4), ch = l & 15;
        bf16x8 vv = *(const bf16x8*)(Vs + (w * 32 + row) * 136 + ch * 8);
        *(bf16x8*)(AO + (brow + qb + w * 32 + row) * 2048 + h * 128 + ch * 8) = vv;
    }
}

extern "C" void kernel_launch(void* const* d_in, const int* in_sizes, int n_in,
                              void* d_out, int out_size, void* d_ws, size_t ws_size,
                              hipStream_t stream)
{
    (void)in_sizes; (void)n_in; (void)out_size; (void)ws_size;
    const void* X    = d_in[0];
    const int*  mask = (const int*)d_in[1];
    const void* Wqkv = d_in[2];
    const void* bqkv = d_in[3];
    const void* Wo   = d_in[4];
    const void* bo   = d_in[5];

    int*      flag  = (int*)d_ws;
    ushort_t* Xc    = (ushort_t*)d_ws + 16;
    ushort_t* Wqkvc = Xc + 8388608;
    ushort_t* bqkvc = Wqkvc + 12582912;
    ushort_t* Woc   = bqkvc + 6144;
    ushort_t* boc   = Woc + 4194304;
    ushort_t* qkv   = boc + 2048;
    ushort_t* Vt    = Wqkvc;   // reuse: Wqkv dead after gemm1
    ushort_t* AO    = Xc;      // reuse: X dead after gemm1

    detect_kernel<<<1, 256, 0, stream>>>((const ushort_t*)Wqkv, flag);
    convert_kernel<<<4096, 256, 0, stream>>>(X,    Xc,    8388608,  flag);
    convert_kernel<<<6144, 256, 0, stream>>>(Wqkv, Wqkvc, 12582912, flag);
    convert_kernel<<<3,    256, 0, stream>>>(bqkv, bqkvc, 6144,     flag);
    convert_kernel<<<2048, 256, 0, stream>>>(Wo,   Woc,   4194304,  flag);
    convert_kernel<<<1,    256, 0, stream>>>(bo,   boc,   2048,     flag);

    gemm256_bt_bias<<<dim3(6144 / 256, 4096 / 256), 512, 0, stream>>>(Xc, Wqkvc, bqkvc, qkv, 4096, 6144, 2048);
    rope_kernel<<<4096, 256, 0, stream>>>(qkv);
    vtrans_kernel<<<1024, 256, 0, stream>>>(qkv, Vt);
    flash_kernel<<<dim3(16, 16, 2), 256, 0, stream>>>(qkv, Vt, mask, AO);
    gemm_bt_bias_out<<<dim3(2048 / 128, 4096 / 128), 256, 0, stream>>>(AO, Woc, boc, d_out, 4096, 2048, 2048, flag);
}

// Round 2
// 578.913 us; speedup vs baseline: 1.1325x; 1.0518x over previous
//
#include <hip/hip_runtime.h>
#include <hip/hip_bf16.h>
#include <math.h>

typedef __bf16 bf16x8 __attribute__((ext_vector_type(8)));
typedef float  f32x4  __attribute__((ext_vector_type(4)));
typedef float  f32x16 __attribute__((ext_vector_type(16)));
typedef unsigned short ushort_t;
typedef ushort_t us4 __attribute__((ext_vector_type(4)));

#define MFMA16(a, b, c) __builtin_amdgcn_mfma_f32_16x16x32_bf16((a), (b), (c), 0, 0, 0)
#define MFMA32(a, b, c) __builtin_amdgcn_mfma_f32_32x32x16_bf16((a), (b), (c), 0, 0, 0)

__device__ __forceinline__ float bf2f(ushort_t h) {
    union { unsigned u; float f; } v; v.u = ((unsigned)h) << 16; return v.f;
}
__device__ __forceinline__ ushort_t f2bf(float x) {
    union { float f; unsigned u; } v; v.f = x;
    unsigned r = v.u + 0x7FFFu + ((v.u >> 16) & 1u);
    return (ushort_t)(r >> 16);
}
// async global->LDS, 16B per lane. LDS dest must be wave-uniform base + lane*16.
__device__ __forceinline__ void gl2lds16(const void* g, void* l) {
    __builtin_amdgcn_global_load_lds((__attribute__((address_space(1))) void*)(g),
                                     (__attribute__((address_space(3))) void*)(l),
                                     16, 0, 0);
}

// ---------------------------------------------------------------------------
// Dtype detector (round-3 verified: flag=1 fires, inputs are fp32).
// ---------------------------------------------------------------------------
__global__ __launch_bounds__(256) void detect_kernel(const ushort_t* __restrict__ w, int* flag)
{
    __shared__ int cnt[256];
    const int t = threadIdx.x;
    int c = 0;
    for (int i = t; i < 65536; i += 256) {
        const unsigned hw = w[i];
        const unsigned e = (hw >> 7) & 0xFFu;
        if (e == 0xFFu || (e == 0u && (hw & 0x7Fu) != 0u)) c++;
    }
    cnt[t] = c;
    __syncthreads();
    for (int s = 128; s > 0; s >>= 1) {
        if (t < s) cnt[t] += cnt[t + s];
        __syncthreads();
    }
    if (t == 0) flag[0] = (cnt[0] >= 8) ? 1 : 0;
}

__global__ __launch_bounds__(256) void convert_kernel(const void* __restrict__ src,
                                                      ushort_t* __restrict__ dst,
                                                      int n, const int* __restrict__ flag)
{
    const int i0 = (blockIdx.x * 256 + threadIdx.x) * 8;
    if (i0 + 8 > n) return;
    if (flag[0]) {
        const f32x4 a = *(const f32x4*)((const float*)src + i0);
        const f32x4 b = *(const f32x4*)((const float*)src + i0 + 4);
        ushort_t o[8];
        o[0]=f2bf(a[0]); o[1]=f2bf(a[1]); o[2]=f2bf(a[2]); o[3]=f2bf(a[3]);
        o[4]=f2bf(b[0]); o[5]=f2bf(b[1]); o[6]=f2bf(b[2]); o[7]=f2bf(b[3]);
        *(bf16x8*)(dst + i0) = *(const bf16x8*)o;
    } else {
        *(bf16x8*)(dst + i0) = *(const bf16x8*)((const ushort_t*)src + i0);
    }
}

// ---------------------------------------------------------------------------
// 256x256-tile 8-phase GEMM, C = A * B^T + bias (bf16 in/out). (round-0, verified)
// ---------------------------------------------------------------------------
__global__ __launch_bounds__(512, 2) void gemm256_bt_bias(
    const ushort_t* __restrict__ A, const ushort_t* __restrict__ B,
    const ushort_t* __restrict__ bias, ushort_t* __restrict__ C,
    int M, int N, int K)
{
    __shared__ __align__(16) ushort_t SM[65536];   // 4 slots x (8192 A + 8192 B) ushorts
    const int tid = threadIdx.x;
    const int l = tid & 63, ln = l & 15, q2 = l >> 4;
    const int w = tid >> 6, wm = w >> 2, wn = w & 3;
    const int m0 = blockIdx.y * 256, n0 = blockIdx.x * 256;
    const int NT = K >> 6;

#define STG_A256(slot, kbase, o) do { \
    const int s_ = (o) * 512 + tid; const int r_ = s_ >> 2; \
    const int q_ = (s_ & 3) ^ ((r_ >> 1) & 3); \
    gl2lds16(A + (size_t)(m0 + r_) * K + (kbase) + q_ * 8, \
             SM + (slot) * 16384 + s_ * 8); } while (0)
#define STG_B256(slot, kbase, o) do { \
    const int s_ = (o) * 512 + tid; const int r_ = s_ >> 2; \
    const int q_ = (s_ & 3) ^ ((r_ >> 1) & 3); \
    gl2lds16(B + (size_t)(n0 + r_) * K + (kbase) + q_ * 8, \
             SM + (slot) * 16384 + 8192 + s_ * 8); } while (0)
#define DSA256(slot, row) (*(const bf16x8*)(SM + (slot) * 16384 + (row) * 32 + ((q2 ^ (((row) >> 1) & 3)) << 3)))
#define DSB256(slot, row) (*(const bf16x8*)(SM + (slot) * 16384 + 8192 + (row) * 32 + ((q2 ^ (((row) >> 1) & 3)) << 3)))
#define BAR256() asm volatile("s_barrier" ::: "memory")

    f32x4 acc[8][4];
    const f32x4 z4 = {0.f, 0.f, 0.f, 0.f};
#pragma unroll
    for (int i = 0; i < 8; i++)
#pragma unroll
        for (int j = 0; j < 4; j++) acc[i][j] = z4;

    STG_A256(0, 0, 0);  STG_A256(0, 0, 1);  STG_B256(0, 0, 0);  STG_B256(0, 0, 1);
    STG_A256(1, 32, 0); STG_A256(1, 32, 1); STG_B256(1, 32, 0); STG_B256(1, 32, 1);
    if (NT > 1) STG_A256(2, 64, 0);
    asm volatile("s_waitcnt vmcnt(5)" ::: "memory");
    BAR256();

    for (int t = 0; t < NT; ++t) {
        const int s0 = (2 * t) & 3, s1 = (2 * t + 1) & 3;
        const int sA = (2 * t + 2) & 3, sB = (2 * t + 3) & 3;
        const int kA = (t + 1) << 6, kB = kA + 32, kC = (t + 2) << 6;
        const bool stAB = (t < NT - 1), stC = (t < NT - 2);
        const int rA0 = wm * 128, rA1 = wm * 128 + 64, rB = wn * 64;
        bf16x8 a0[4], a1[4], b00[2], b01[2], b10[2], b11[2];

        // ---- p0
#pragma unroll
        for (int ii = 0; ii < 4; ii++) a0[ii] = DSA256(s0, rA0 + ii * 16 + ln);
        b00[0] = DSB256(s0, rB + ln);
        b00[1] = DSB256(s0, rB + 16 + ln);
        if (stAB) STG_A256(sA, kA, 1);
        __builtin_amdgcn_s_setprio(1);
#pragma unroll
        for (int ii = 0; ii < 4; ii++) {
            acc[ii][0] = MFMA16(a0[ii], b00[0], acc[ii][0]);
            acc[ii][1] = MFMA16(a0[ii], b00[1], acc[ii][1]);
        }
        __builtin_amdgcn_s_setprio(0);
        if (stAB) { asm volatile("s_waitcnt vmcnt(2)" ::: "memory"); }
        else      { asm volatile("s_waitcnt vmcnt(0)" ::: "memory"); }
        BAR256();

        // ---- p1
#pragma unroll
        for (int ii = 0; ii < 4; ii++) a1[ii] = DSA256(s1, rA0 + ii * 16 + ln);
        b01[0] = DSB256(s1, rB + ln);
        b01[1] = DSB256(s1, rB + 16 + ln);
        if (stAB) STG_B256(sA, kA, 0);
        __builtin_amdgcn_s_setprio(1);
#pragma unroll
        for (int ii = 0; ii < 4; ii++) {
            acc[ii][0] = MFMA16(a1[ii], b01[0], acc[ii][0]);
            acc[ii][1] = MFMA16(a1[ii], b01[1], acc[ii][1]);
        }
        __builtin_amdgcn_s_setprio(0);
        BAR256();

        // ---- p2
        b10[0] = DSB256(s0, rB + 32 + ln);
        b10[1] = DSB256(s0, rB + 48 + ln);
        if (stAB) STG_B256(sA, kA, 1);
        __builtin_amdgcn_s_setprio(1);
#pragma unroll
        for (int ii = 0; ii < 4; ii++) {
            acc[ii][2] = MFMA16(a0[ii], b10[0], acc[ii][2]);
            acc[ii][3] = MFMA16(a0[ii], b10[1], acc[ii][3]);
        }
        __builtin_amdgcn_s_setprio(0);
        BAR256();

        // ---- p3
        b11[0] = DSB256(s1, rB + 32 + ln);
        b11[1] = DSB256(s1, rB + 48 + ln);
        if (stAB) STG_A256(sB, kB, 0);
        __builtin_amdgcn_s_setprio(1);
#pragma unroll
        for (int ii = 0; ii < 4; ii++) {
            acc[ii][2] = MFMA16(a1[ii], b11[0], acc[ii][2]);
            acc[ii][3] = MFMA16(a1[ii], b11[1], acc[ii][3]);
        }
        __builtin_amdgcn_s_setprio(0);
        BAR256();

        // ---- p4
#pragma unroll
        for (int ii = 0; ii < 4; ii++) a0[ii] = DSA256(s0, rA1 + ii * 16 + ln);
        if (stAB) STG_A256(sB, kB, 1);
        __builtin_amdgcn_s_setprio(1);
#pragma unroll
        for (int ii = 0; ii < 4; ii++) {
            acc[4 + ii][2] = MFMA16(a0[ii], b10[0], acc[4 + ii][2]);
            acc[4 + ii][3] = MFMA16(a0[ii], b10[1], acc[4 + ii][3]);
        }
        __builtin_amdgcn_s_setprio(0);
        BAR256();

        // ---- p5
#pragma unroll
        for (int ii = 0; ii < 4; ii++) a1[ii] = DSA256(s1, rA1 + ii * 16 + ln);
        if (stAB) STG_B256(sB, kB, 0);
        __builtin_amdgcn_s_setprio(1);
#pragma unroll
        for (int ii = 0; ii < 4; ii++) {
            acc[4 + ii][2] = MFMA16(a1[ii], b11[0], acc[4 + ii][2]);
            acc[4 + ii][3] = MFMA16(a1[ii], b11[1], acc[4 + ii][3]);
        }
        __builtin_amdgcn_s_setprio(0);
        BAR256();

        // ---- p6
        if (stAB) STG_B256(sB, kB, 1);
        __builtin_amdgcn_s_setprio(1);
#pragma unroll
        for (int ii = 0; ii < 4; ii++) {
            acc[4 + ii][0] = MFMA16(a0[ii], b00[0], acc[4 + ii][0]);
            acc[4 + ii][1] = MFMA16(a0[ii], b00[1], acc[4 + ii][1]);
        }
        __builtin_amdgcn_s_setprio(0);
        BAR256();

        // ---- p7
        if (stC) STG_A256(s0, kC, 0);
        __builtin_amdgcn_s_setprio(1);
#pragma unroll
        for (int ii = 0; ii < 4; ii++) {
            acc[4 + ii][0] = MFMA16(a1[ii], b01[0], acc[4 + ii][0]);
            acc[4 + ii][1] = MFMA16(a1[ii], b01[1], acc[4 + ii][1]);
        }
        __builtin_amdgcn_s_setprio(0);
        if (t < NT - 2)       { asm volatile("s_waitcnt vmcnt(5)" ::: "memory"); }
        else if (t == NT - 2) { asm volatile("s_waitcnt vmcnt(4)" ::: "memory"); }
        BAR256();
    }

#pragma unroll
    for (int j = 0; j < 4; j++) {
        const int n = n0 + wn * 64 + j * 16 + ln;
        const float bv = bf2f(bias[n]);
#pragma unroll
        for (int i = 0; i < 8; i++) {
            const int mrow = m0 + wm * 128 + i * 16 + q2 * 4;
#pragma unroll
            for (int r = 0; r < 4; r++)
                C[(size_t)(mrow + r) * N + n] = f2bf(acc[i][j][r] + bv);
        }
    }
#undef STG_A256
#undef STG_B256
#undef DSA256
#undef DSB256
#undef BAR256
}

// ---------------------------------------------------------------------------
// Final GEMM: fp32 output when flag=1 (verified), bf16 otherwise. (m97-style)
// ---------------------------------------------------------------------------
__global__ __launch_bounds__(256) void gemm_bt_bias_out(
    const ushort_t* __restrict__ A, const ushort_t* __restrict__ B,
    const ushort_t* __restrict__ bias, void* __restrict__ C,
    int M, int N, int K, const int* __restrict__ flag)
{
    __shared__ __align__(16) ushort_t As[128 * 32];
    __shared__ __align__(16) ushort_t Bs[128 * 32];
    const int tid = threadIdx.x;
    const int w = tid >> 6, l = tid & 63, q = l >> 4, ln = l & 15;
    const int wm = w >> 1, wn = w & 1;
    const int m0 = blockIdx.y * 128, n0 = blockIdx.x * 128;
    const int sr = tid >> 2;
    const int sc = (tid & 3) * 8;

    f32x4 acc[4][4];
    const f32x4 z4 = {0.f, 0.f, 0.f, 0.f};
    for (int i = 0; i < 4; i++) for (int j = 0; j < 4; j++) acc[i][j] = z4;

    for (int k0 = 0; k0 < K; k0 += 32) {
        __syncthreads();
        gl2lds16(A + (size_t)(m0 + sr) * K + k0 + sc,       As + sr * 32 + sc);
        gl2lds16(A + (size_t)(m0 + 64 + sr) * K + k0 + sc,  As + (64 + sr) * 32 + sc);
        gl2lds16(B + (size_t)(n0 + sr) * K + k0 + sc,       Bs + sr * 32 + sc);
        gl2lds16(B + (size_t)(n0 + 64 + sr) * K + k0 + sc,  Bs + (64 + sr) * 32 + sc);
        __syncthreads();
        bf16x8 a[4], bb[4];
        for (int i = 0; i < 4; i++)
            a[i]  = *(const bf16x8*)(As + (wm * 64 + i * 16 + ln) * 32 + q * 8);
        for (int j = 0; j < 4; j++)
            bb[j] = *(const bf16x8*)(Bs + (wn * 64 + j * 16 + ln) * 32 + q * 8);
        for (int i = 0; i < 4; i++)
            for (int j = 0; j < 4; j++)
                acc[i][j] = MFMA16(a[i], bb[j], acc[i][j]);
    }
    const int f = flag[0];
    for (int j = 0; j < 4; j++) {
        const int n = n0 + wn * 64 + j * 16 + ln;
        const float bv = bf2f(bias[n]);
        for (int i = 0; i < 4; i++) {
            const int mrow = m0 + wm * 64 + i * 16 + q * 4;
            for (int r = 0; r < 4; r++) {
                const float val = acc[i][j][r] + bv;
                const size_t idx = (size_t)(mrow + r) * N + n;
                if (f) ((float*)C)[idx] = val;
                else   ((ushort_t*)C)[idx] = f2bf(val);
            }
        }
    }
}

// ---------------------------------------------------------------------------
// RoPE (unchanged, verified).
// ---------------------------------------------------------------------------
__global__ __launch_bounds__(256) void rope_kernel(ushort_t* qkv)
{
    const int bs = blockIdx.x;
    const int s = bs & 2047;
    const int t = threadIdx.x;
    const size_t base = (size_t)bs * 6144;
    float cv[8], sv[8], qa[8], qp[8], ka[8], kp[8];
    for (int u = 0; u < 8; u++) {
        const int e = u * 256 + t;
        const int j = e & 127;
        const int p = (j < 64) ? (2 * j + 1) : (2 * (j - 64));
        const int hb = e - j;
        const float ang = powf(10000.0f, -(float)(2 * (j >> 1)) / 2048.0f);
        sincosf((float)s * ang, &sv[u], &cv[u]);
        qa[u] = bf2f(qkv[base + hb + j]);
        qp[u] = bf2f(qkv[base + hb + p]);
        ka[u] = bf2f(qkv[base + 2048 + hb + j]);
        kp[u] = bf2f(qkv[base + 2048 + hb + p]);
    }
    __syncthreads();
    for (int u = 0; u < 8; u++) {
        const int e = u * 256 + t;
        const int j = e & 127;
        const int hb = e - j;
        const float sg = (j < 64) ? -1.0f : 1.0f;
        qkv[base + hb + j]        = f2bf(cv[u] * qa[u] + sv[u] * sg * qp[u]);
        qkv[base + 2048 + hb + j] = f2bf(cv[u] * ka[u] + sv[u] * sg * kp[u]);
    }
}

// ---------------------------------------------------------------------------
// Vt[b,h,d,s] = qkv[b,s,2,h,d] (unchanged, verified).
// ---------------------------------------------------------------------------
__global__ __launch_bounds__(256) void vtrans_kernel(const ushort_t* __restrict__ qkv,
                                                     ushort_t* __restrict__ Vt)
{
    __shared__ ushort_t tile[64][130];
    const int blk = blockIdx.x;
    const int st = blk & 31, h = (blk >> 5) & 15, b = blk >> 9;
    const int t = threadIdx.x;
    for (int i = 0; i < 32; i++) {
        const int e = i * 256 + t;
        const int r = e >> 7, c = e & 127;
        tile[r][c] = qkv[(size_t)(b * 2048 + st * 64 + r) * 6144 + 4096 + h * 128 + c];
    }
    __syncthreads();
    const int d = t >> 1, s0 = (t & 1) * 32;
    const size_t obase = ((size_t)(b * 16 + h) * 128 + d) * 2048 + st * 64 + s0;
    for (int k = 0; k < 32; k++)
        Vt[obase + k] = tile[s0 + k][d];
}

// ---------------------------------------------------------------------------
// Flash attention v3 — S^T formulation, 32x32x16 MFMA, m214-ladder techniques:
//   * XOR-swizzled unpadded Ks[64][128] / Vs[128][64] (slot ^= row&15 / row&7):
//     conflict-free b128 reads AND writes (8 lanes per 4-bank group, derived).
//     Same involution on write and read => logical identity.
//   * T14 async-STAGE: next tile's 8x b128 K/V global loads issued after this
//     tile's ds_writes; raw s_barrier + lgkmcnt(0) only (NO vmcnt drain at the
//     barrier) so HBM latency hides under QK^T+softmax+PV.
//   * T12 in-register P: cvt_pk_bf16_f32 + permlane32_swap (vdst.hi<->vsrc.lo)
//     replaces the Ps LDS round-trip. Frag element j (lane q2) = lane(j>>2)'s
//     p[bb + q2*4 + (j&3)], bb = (kb>>1)*16 + (kb&1)*8  [derived from the
//     verified Ps-path mapping]. swap(pk(p[bb],p[bb+1]), pk(p[bb+4],p[bb+5]))
//     -> (word j0j1, word j4j5).
//   * T13 defer-max (THR=8) + all-valid mask fast path + T5 setprio on MFMA.
//   LDS 70656 -> 32768 (epilogue overlays SM as [128][128] swizzled).
// ---------------------------------------------------------------------------
__global__ __launch_bounds__(256, 2) void flash_kernel(
    const ushort_t* __restrict__ qkv, const ushort_t* __restrict__ Vt,
    const int* __restrict__ mask, ushort_t* __restrict__ AO)
{
    __shared__ __align__(16) ushort_t SM[16384];   // 32 KiB
    ushort_t* Ks = SM;          // [64][128] bf16, 16B-unit swizzle ^(row&15)
    ushort_t* Vs = SM + 8192;   // [128][64] bf16, 16B-unit swizzle ^(row&7)
    const int t = threadIdx.x;
    const int w = t >> 6, l = t & 63, lq = l & 31, q2 = l >> 5;
    const int qb = blockIdx.x * 128, h = blockIdx.y, b = blockIdx.z;
    const size_t brow = (size_t)b * 2048;
    const float scale = 0.08838834764831845f;   // 1/sqrt(128)
    const int qrow = qb + w * 32 + lq;
    const size_t vbase = (size_t)(b * 16 + h) * 128;

    // Q as register-resident B-frags
    bf16x8 qf[8];
#pragma unroll
    for (int kb = 0; kb < 8; kb++)
        qf[kb] = *(const bf16x8*)(qkv + (brow + qrow) * 6144 + h * 128 + kb * 16 + q2 * 8);

    float m_old = -1e30f, lsum = 0.f;
    f32x16 acc_o[4];
#pragma unroll
    for (int dt = 0; dt < 4; dt++)
#pragma unroll
        for (int r = 0; r < 16; r++) acc_o[dt][r] = 0.f;

    // T14 staging registers; issue tile 0
    bf16x8 kst[4], vst[4];
#pragma unroll
    for (int i = 0; i < 4; i++) {
        const int s_ = i * 256 + t; const int row = s_ >> 4; const int u = s_ & 15;
        kst[i] = *(const bf16x8*)(qkv + (brow + row) * 6144 + 2048 + h * 128 + u * 8);
    }
#pragma unroll
    for (int i = 0; i < 4; i++) {
        const int s_ = i * 256 + t; const int row = s_ >> 3; const int u = s_ & 7;
        vst[i] = *(const bf16x8*)(Vt + (vbase + row) * 2048 + u * 8);
    }

    for (int s0 = 0; s0 < 2048; s0 += 64) {
        const int mk = mask[brow + s0 + l];
        const unsigned long long bm = __ballot(mk != 0);
        asm volatile("s_waitcnt lgkmcnt(0)" ::: "memory");
        asm volatile("s_barrier" ::: "memory");          // all waves done reading prev tile
        // write staged K (swizzled), V (swizzled)
#pragma unroll
        for (int i = 0; i < 4; i++) {
            const int s_ = i * 256 + t; const int row = s_ >> 4; const int u = s_ & 15;
            *(bf16x8*)(Ks + row * 128 + ((u ^ (row & 15)) << 3)) = kst[i];
        }
#pragma unroll
        for (int i = 0; i < 4; i++) {
            const int s_ = i * 256 + t; const int row = s_ >> 3; const int u = s_ & 7;
            *(bf16x8*)(Vs + row * 64 + ((u ^ (row & 7)) << 3)) = vst[i];
        }
        // issue next tile's loads (stay in flight across the barrier, under compute)
        if (s0 + 64 < 2048) {
#pragma unroll
            for (int i = 0; i < 4; i++) {
                const int s_ = i * 256 + t; const int row = s_ >> 4; const int u = s_ & 15;
                kst[i] = *(const bf16x8*)(qkv + (brow + s0 + 64 + row) * 6144 + 2048 + h * 128 + u * 8);
            }
#pragma unroll
            for (int i = 0; i < 4; i++) {
                const int s_ = i * 256 + t; const int row = s_ >> 3; const int u = s_ & 7;
                vst[i] = *(const bf16x8*)(Vt + (vbase + row) * 2048 + s0 + 64 + u * 8);
            }
        }
        asm volatile("s_waitcnt lgkmcnt(0)" ::: "memory");  // ds_writes drained (NOT vmcnt)
        asm volatile("s_barrier" ::: "memory");             // writes visible

        // S^T = K @ Q^T
        f32x16 sa[2];
#pragma unroll
        for (int mt = 0; mt < 2; mt++) {
#pragma unroll
            for (int r = 0; r < 16; r++) sa[mt][r] = 0.f;
            const int row = mt * 32 + lq;
            __builtin_amdgcn_s_setprio(1);
#pragma unroll
            for (int kb = 0; kb < 8; kb++) {
                bf16x8 a = *(const bf16x8*)(Ks + row * 128 + (((kb * 2 + q2) ^ (row & 15)) << 3));
                sa[mt] = MFMA32(a, qf[kb], sa[mt]);
            }
            __builtin_amdgcn_s_setprio(0);
        }
        // online softmax (per-lane q-row; partner lane l^32 shares the row)
        float p[32];
        float mr = -1e30f;
        if (bm == ~0ull) {
#pragma unroll
            for (int mt = 0; mt < 2; mt++)
#pragma unroll
                for (int r = 0; r < 16; r++) {
                    const float v = sa[mt][r] * scale;
                    p[mt * 16 + r] = v;
                    mr = fmaxf(mr, v);
                }
        } else {
#pragma unroll
            for (int mt = 0; mt < 2; mt++)
#pragma unroll
                for (int r = 0; r < 16; r++) {
                    const int srow = mt * 32 + (r & 3) + 8 * (r >> 2) + 4 * q2;
                    const float bias = ((bm >> srow) & 1ull) ? 0.f : -1e9f;
                    const float v = sa[mt][r] * scale + bias;
                    p[mt * 16 + r] = v;
                    mr = fmaxf(mr, v);
                }
        }
        mr = fmaxf(mr, __shfl_xor(mr, 32, 64));
        if (!__all(mr <= m_old + 8.0f)) {        // T13 defer-max
            const float mnew = fmaxf(m_old, mr);
            const float alpha = __expf(m_old - mnew);
            lsum *= alpha;
#pragma unroll
            for (int dt = 0; dt < 4; dt++)
#pragma unroll
                for (int r = 0; r < 16; r++) acc_o[dt][r] *= alpha;
            m_old = mnew;
        }
        float rs = 0.f;
#pragma unroll
        for (int i = 0; i < 32; i++) { p[i] = __expf(p[i] - m_old); rs += p[i]; }
        rs += __shfl_xor(rs, 32, 64);
        lsum += rs;

        // O^T += V^T @ P^T  (P in-register via cvt_pk + permlane32_swap)
#pragma unroll
        for (int kb = 0; kb < 4; kb++) {
            const int bb = (kb >> 1) * 16 + (kb & 1) * 8;
            unsigned w01, w23, w45, w67;
            asm("v_cvt_pk_bf16_f32 %0, %1, %2" : "=v"(w01) : "v"(p[bb + 0]), "v"(p[bb + 1]));
            asm("v_cvt_pk_bf16_f32 %0, %1, %2" : "=v"(w23) : "v"(p[bb + 2]), "v"(p[bb + 3]));
            asm("v_cvt_pk_bf16_f32 %0, %1, %2" : "=v"(w45) : "v"(p[bb + 4]), "v"(p[bb + 5]));
            asm("v_cvt_pk_bf16_f32 %0, %1, %2" : "=v"(w67) : "v"(p[bb + 6]), "v"(p[bb + 7]));
            asm("v_permlane32_swap_b32 %0, %1" : "+v"(w01), "+v"(w45));
            asm("v_permlane32_swap_b32 %0, %1" : "+v"(w23), "+v"(w67));
            union { unsigned u[4]; bf16x8 v8; } pu;
            pu.u[0] = w01; pu.u[1] = w23; pu.u[2] = w45; pu.u[3] = w67;
            __builtin_amdgcn_s_setprio(1);
#pragma unroll
            for (int dt = 0; dt < 4; dt++) {
                const int row = dt * 32 + lq;
                bf16x8 va = *(const bf16x8*)(Vs + row * 64 + (((kb * 2 + q2) ^ (row & 7)) << 3));
                acc_o[dt] = MFMA32(va, pu.v8, acc_o[dt]);
            }
            __builtin_amdgcn_s_setprio(0);
        }
    }
    __syncthreads();   // all PV reads done before epilogue overlays SM
    // epilogue: divide by lsum, transpose O^T -> row-major via SM [128][128] swizzled
    const float inv = (lsum > 0.f) ? 1.0f / lsum : 0.f;
#pragma unroll
    for (int dt = 0; dt < 4; dt++)
#pragma unroll
        for (int r2 = 0; r2 < 4; r2++) {
            us4 ov;
#pragma unroll
            for (int j = 0; j < 4; j++) ov[j] = f2bf(acc_o[dt][r2 * 4 + j] * inv);
            const int row = w * 32 + lq;
            const int unit = dt * 4 + r2;
            *(us4*)(SM + row * 128 + ((unit ^ (row & 15)) << 3) + q2 * 4) = ov;
        }
    __syncthreads();
#pragma unroll
    for (int i = 0; i < 8; i++) {
        const int rl = i * 4 + (l >> 4), ch = l & 15;
        const int row = w * 32 + rl;
        bf16x8 vv = *(const bf16x8*)(SM + row * 128 + ((ch ^ (row & 15)) << 3));
        *(bf16x8*)(AO + (brow + qb + row) * 2048 + h * 128 + ch * 8) = vv;
    }
}

extern "C" void kernel_launch(void* const* d_in, const int* in_sizes, int n_in,
                              void* d_out, int out_size, void* d_ws, size_t ws_size,
                              hipStream_t stream)
{
    (void)in_sizes; (void)n_in; (void)out_size; (void)ws_size;
    const void* X    = d_in[0];
    const int*  mask = (const int*)d_in[1];
    const void* Wqkv = d_in[2];
    const void* bqkv = d_in[3];
    const void* Wo   = d_in[4];
    const void* bo   = d_in[5];

    int*      flag  = (int*)d_ws;
    ushort_t* Xc    = (ushort_t*)d_ws + 16;
    ushort_t* Wqkvc = Xc + 8388608;
    ushort_t* bqkvc = Wqkvc + 12582912;
    ushort_t* Woc   = bqkvc + 6144;
    ushort_t* boc   = Woc + 4194304;
    ushort_t* qkv   = boc + 2048;
    ushort_t* Vt    = Wqkvc;   // reuse: Wqkv dead after gemm1
    ushort_t* AO    = Xc;      // reuse: X dead after gemm1

    detect_kernel<<<1, 256, 0, stream>>>((const ushort_t*)Wqkv, flag);
    convert_kernel<<<4096, 256, 0, stream>>>(X,    Xc,    8388608,  flag);
    convert_kernel<<<6144, 256, 0, stream>>>(Wqkv, Wqkvc, 12582912, flag);
    convert_kernel<<<3,    256, 0, stream>>>(bqkv, bqkvc, 6144,     flag);
    convert_kernel<<<2048, 256, 0, stream>>>(Wo,   Woc,   4194304,  flag);
    convert_kernel<<<1,    256, 0, stream>>>(bo,   boc,   2048,     flag);

    gemm256_bt_bias<<<dim3(6144 / 256, 4096 / 256), 512, 0, stream>>>(Xc, Wqkvc, bqkvc, qkv, 4096, 6144, 2048);
    rope_kernel<<<4096, 256, 0, stream>>>(qkv);
    vtrans_kernel<<<1024, 256, 0, stream>>>(qkv, Vt);
    flash_kernel<<<dim3(16, 16, 2), 256, 0, stream>>>(qkv, Vt, mask, AO);
    gemm_bt_bias_out<<<dim3(2048 / 128, 4096 / 128), 256, 0, stream>>>(AO, Woc, boc, d_out, 4096, 2048, 2048, flag);
}